// Round 21
// baseline (135.370 us; speedup 1.0000x reference)
//
#include <hip/hip_runtime.h>
#include <hip/hip_bf16.h>
#include <math.h>

// Problem: B=2, T=2048, D=1024, H=16, C=64. fp32 in/out, fp16 MFMA internally.
//
// Workspace layout (bytes):
//   xb  @ 0         : x as fp16            (4096x1024)   8388608
//   Wt  @ 8388608   : [Wq;Wkv]^T fp16      (3072x1024)   6291456
//   Wot @ 14680064  : Wo^T fp16            (1024x1024)   2097152
//   cs  @ 16777216  : cos/sin table float2 (2048x32)      524288
//   Qb  @ 17301504  : Q roped*scale fp16 [B][H][T][C]    8388608
//   Kb  @ 25690112  : K roped fp16 [B][H][T][C]          8388608
//   Vt  @ 34078720  : V fp16 [B][H][C][T] (transposed)   8388608
//   AO  @ 42467328  : attention out fp16 [B*T][H*C]      8388608
//
// r21: V staged global->LDS->reg had ZERO reuse (each element consumed once
// per block) -- now loaded global->reg directly (L2-resident per XCD via the
// bh-group swizzle; latency hidden under QKT+softmax). Halves staging issue,
// LDS traffic, and LDS footprint (64->32 KB).

typedef _Float16 half8 __attribute__((ext_vector_type(8)));
typedef _Float16 half4 __attribute__((ext_vector_type(4)));
typedef float f32x4 __attribute__((ext_vector_type(4)));
typedef float f32x16 __attribute__((ext_vector_type(16)));

// OCML native exp2 = raw v_exp_f32, compiler-visible (r16: libm exp2f's
// fixup tail was ~18% of attn VALU; builtin permlane closed the r13/r15
// inline-asm hazard).
extern "C" __device__ float __ocml_native_exp2_f32(float);

__device__ __forceinline__ void gload16(const void* g, void* l) {
  __builtin_amdgcn_global_load_lds(
      (const __attribute__((address_space(1))) void*)g,
      (__attribute__((address_space(3))) void*)l, 16, 0, 0);
}

// ---------------------------------------------------------------- prep
__global__ __launch_bounds__(256) void prep_kernel(
    const float* __restrict__ x, const float* __restrict__ Wq,
    const float* __restrict__ Wkv, const float* __restrict__ Wo,
    _Float16* __restrict__ xb, _Float16* __restrict__ Wt,
    _Float16* __restrict__ Wot, float2* __restrict__ cs)
{
  const int bid = blockIdx.x, t = threadIdx.x;
  if (bid < 2048) {
    size_t i = ((size_t)bid * 256 + t) * 8;
    const float4* p = (const float4*)(x + i);
    float4 a = p[0], b = p[1];
    half8 h;
    h[0] = (_Float16)a.x; h[1] = (_Float16)a.y; h[2] = (_Float16)a.z; h[3] = (_Float16)a.w;
    h[4] = (_Float16)b.x; h[5] = (_Float16)b.y; h[6] = (_Float16)b.z; h[7] = (_Float16)b.w;
    *(half8*)(xb + i) = h;
  } else if (bid < 6144) {
    int tt = bid - 2048;
    const float* src; _Float16* dst; int N, tk, tn;
    if (tt < 1024)      { src = Wq;  dst = Wt;                      N = 1024; tk = tt >> 5; tn = tt & 31; }
    else if (tt < 3072) { tt -= 1024; src = Wkv; dst = Wt + (size_t)1024 * 1024; N = 2048; tk = tt >> 6; tn = tt & 63; }
    else                { tt -= 3072; src = Wo;  dst = Wot;         N = 1024; tk = tt >> 5; tn = tt & 31; }
    __shared__ float tile[32][33];
    const int r = t >> 3, c4 = (t & 7) << 2;
    const float4 v = *(const float4*)(src + (size_t)(tk * 32 + r) * N + tn * 32 + c4);
    tile[r][c4 + 0] = v.x; tile[r][c4 + 1] = v.y; tile[r][c4 + 2] = v.z; tile[r][c4 + 3] = v.w;
    __syncthreads();
    half4 o;
    o[0] = (_Float16)tile[c4 + 0][r];
    o[1] = (_Float16)tile[c4 + 1][r];
    o[2] = (_Float16)tile[c4 + 2][r];
    o[3] = (_Float16)tile[c4 + 3][r];
    *(half4*)(dst + (size_t)(tn * 32 + r) * 1024 + tk * 32 + c4) = o;
  } else {
    int idx = (bid - 6144) * 256 + t;
    int tt = idx >> 5, j = idx & 31;
    float p = powf(10000.0f, (float)(2 * j) * (1.0f / 64.0f));
    float ang = (float)tt / p;
    float sn, cn;
    sincosf(ang, &sn, &cn);
    cs[idx] = make_float2(cn, sn);
  }
}

// ------------------------------------------------------------ GEMM core
__device__ __forceinline__ void gemm_core(
    const _Float16* __restrict__ A, const _Float16* __restrict__ B,
    _Float16* __restrict__ As, _Float16* __restrict__ Bs,
    int row0, int col0, f32x4 (&acc)[4][4])
{
  const int t = threadIdx.x;
  const int l = t & 63;
  const int l15 = l & 15, lg = l >> 4;
  const int w = t >> 6;
  const int wr = (w >> 1) * 64, wc = (w & 1) * 64;
#pragma unroll
  for (int m = 0; m < 4; ++m)
#pragma unroll
    for (int n = 0; n < 4; ++n)
      acc[m][n] = (f32x4){0.f, 0.f, 0.f, 0.f};

  const int lsub = l >> 3;
  const int lcb  = (l & 7) * 16;

  for (int k0 = 0; k0 < 1024; k0 += 64) {
    __syncthreads();
#pragma unroll
    for (int i = 0; i < 4; ++i) {
      const int rb = i * 32 + w * 8;
      const int r = rb + lsub;
      const int swz = lcb ^ ((r & 7) << 4);
      gload16((const char*)A + (size_t)(row0 + r) * 2048 + (size_t)k0 * 2 + swz,
              (char*)As + rb * 128);
      gload16((const char*)B + (size_t)(col0 + r) * 2048 + (size_t)k0 * 2 + swz,
              (char*)Bs + rb * 128);
    }
    __syncthreads();
#pragma unroll
    for (int kk = 0; kk < 2; ++kk) {
      const int kb = kk * 64 + (lg << 4);
      half8 af[4], bf[4];
#pragma unroll
      for (int m = 0; m < 4; ++m) {
        const int row = wr + 16 * m + l15;
        af[m] = *(const half8*)((const char*)As + row * 128 + (kb ^ ((row & 7) << 4)));
      }
#pragma unroll
      for (int n = 0; n < 4; ++n) {
        const int col = wc + 16 * n + l15;
        bf[n] = *(const half8*)((const char*)Bs + col * 128 + (kb ^ ((col & 7) << 4)));
      }
#pragma unroll
      for (int m = 0; m < 4; ++m)
#pragma unroll
        for (int n = 0; n < 4; ++n)
          acc[m][n] = __builtin_amdgcn_mfma_f32_16x16x32_f16(af[m], bf[n], acc[m][n], 0, 0, 0);
    }
  }
}

// ------------------------------------------------------- GEMM1: QKV+RoPE
// Q pre-scaled by (1/sqrt(C))*log2(e). V blocks (col0g >= 2048) computed
// TRANSPOSED (gemm_core with A/B swapped) so Vt[c][t] stores are contiguous
// in t instead of a per-lane 2B scatter (r17: part of the -5.3us GEMM win).
__global__ __launch_bounds__(256) void gemm_qkv(
    const _Float16* __restrict__ xb, const _Float16* __restrict__ Wt,
    const float* __restrict__ bq, const float* __restrict__ bkv,
    const float2* __restrict__ cs,
    _Float16* __restrict__ Qb, _Float16* __restrict__ Kb, _Float16* __restrict__ Vt)
{
  __shared__ __align__(16) _Float16 As[128 * 64], Bs[128 * 64];
  f32x4 acc[4][4];
  const int row0 = blockIdx.x * 128, col0g = blockIdx.y * 128;
  const int t = threadIdx.x, l = t & 63, l15 = l & 15, lg = l >> 4, w = t >> 6;

  if (col0g < 2048) {
    gemm_core(xb, Wt, As, Bs, row0, col0g, acc);
    const int wrow = row0 + (w >> 1) * 64;
    const int ncol = col0g + (w & 1) * 64;
    const int seg = ncol >> 10;              // 0:q 1:k
    const int hcol = ncol & 1023;
    const int h = hcol >> 6;
    const float* bias = (seg == 0) ? bq : bkv;
    _Float16* dst = (seg == 0) ? Qb : Kb;
    const float qs = (seg == 0) ? 0.18033688011112042f : 1.0f;  // sl2e or 1
    const float b0 = bias[hcol + l15],      b1 = bias[hcol + 16 + l15];
    const float b2 = bias[hcol + 32 + l15], b3 = bias[hcol + 48 + l15];
#pragma unroll
    for (int m = 0; m < 4; ++m) {
#pragma unroll
      for (int reg = 0; reg < 4; ++reg) {
        const int row = wrow + 16 * m + lg * 4 + reg;
        const int bb = row >> 11, tt = row & 2047;
        const float2 cs0 = cs[tt * 32 + l15];
        const float2 cs1 = cs[tt * 32 + 16 + l15];
        const float v0 = acc[m][0][reg] + b0;
        const float v1 = acc[m][1][reg] + b1;
        const float v2 = acc[m][2][reg] + b2;
        const float v3 = acc[m][3][reg] + b3;
        const size_t base = ((size_t)(bb * 16 + h) * 2048 + tt) * 64;
        dst[base + l15]      = (_Float16)((v0 * cs0.x - v2 * cs0.y) * qs);
        dst[base + 16 + l15] = (_Float16)((v1 * cs1.x - v3 * cs1.y) * qs);
        dst[base + 32 + l15] = (_Float16)((v2 * cs0.x + v0 * cs0.y) * qs);
        dst[base + 48 + l15] = (_Float16)((v3 * cs1.x + v1 * cs1.y) * qs);
      }
    }
  } else {
    gemm_core(Wt, xb, As, Bs, col0g, row0, acc);
    const int vcol = (col0g - 2048) + (w >> 1) * 64;   // wave's base v-channel
    const int tbase = row0 + (w & 1) * 64;             // wave's base t
#pragma unroll
    for (int m = 0; m < 4; ++m) {
#pragma unroll
      for (int reg = 0; reg < 4; ++reg) {
        const int vchan = vcol + 16 * m + lg * 4 + reg;      // 0..1023
        const float bv = bkv[1024 + vchan];
        const size_t crow = (size_t)(vchan >> 6) * 64 + (vchan & 63);
#pragma unroll
        for (int n = 0; n < 4; ++n) {
          const int tg = tbase + 16 * n + l15;
          const int bb2 = tg >> 11, tt2 = tg & 2047;
          Vt[((size_t)bb2 * 1024 + crow) * 2048 + tt2] =
              (_Float16)(acc[m][n][reg] + bv);
        }
      }
    }
  }
}

// ------------------------------------------------------- flash attention
// r18 body (KVBLK=128, two 64-row sub-tiles per barrier region, native exp2
// + builtin permlane) with V DIRECT FROM GLOBAL (r21): V had zero LDS reuse,
// so it's loaded straight to registers at the top of each sub-tile (L2-hot
// per-XCD; ~200cy latency hidden under QKT+softmax ~1000cy). K-only staging
// halves gload_lds issue and LDS traffic; LDS 64 -> 32 KB.
__global__ __launch_bounds__(256, 2) void attn_kernel(
    const _Float16* __restrict__ Qb, const _Float16* __restrict__ Kb,
    const _Float16* __restrict__ Vt, _Float16* __restrict__ AO)
{
  __shared__ __align__(16) _Float16 Ks[4][64 * 64];                 // 32 KB
  // bijective swizzle of 512 blocks: 8 XCDs x (4 bh x 16 qtiles)
  const int lin = blockIdx.x + (blockIdx.y << 4);
  const int xcd = lin & 7, idx = lin >> 3;          // idx 0..63
  const int bh = (xcd << 2) + (idx >> 4);
  const int qblk = (idx & 15) << 7;                 // 128 q rows per block
  const int t = threadIdx.x, l = t & 63, l31 = l & 31, hh = l >> 5, w = t >> 6;
  const _Float16* Qg = Qb + (size_t)bh * 2048 * 64;
  const _Float16* Kg = Kb + (size_t)bh * 2048 * 64;
  const _Float16* Vg = Vt + (size_t)bh * 64 * 2048;

  // Q fragments (B operand, 32x32x16): col=q=l31, k(c) = 32*t4 + 16*hh + j
  const int qrow = qblk + w * 32 + l31;
  half8 qf[4];
#pragma unroll
  for (int t4 = 0; t4 < 4; ++t4)
    qf[t4] = *(const half8*)((const char*)Qg + (size_t)qrow * 128 + t4 * 32 + hh * 16);

  f32x16 oacc[2], lacc;
#pragma unroll
  for (int cc = 0; cc < 2; ++cc)
#pragma unroll
    for (int r = 0; r < 16; ++r) oacc[cc][r] = 0.f;
#pragma unroll
  for (int r = 0; r < 16; ++r) lacc[r] = 0.f;
  const half8 onesf = {(_Float16)1, (_Float16)1, (_Float16)1, (_Float16)1,
                       (_Float16)1, (_Float16)1, (_Float16)1, (_Float16)1};

  const int lsub = l >> 3;
  const int lcb  = (l & 7) * 16;

#define STAGE(s0, buf)                                                          \
  {                                                                             \
    _Pragma("unroll")                                                           \
    for (int i = 0; i < 2; ++i) {                                               \
      const int rb = w * 16 + i * 8;                                            \
      const int r = rb + lsub;                                                  \
      const int swz = lcb ^ ((r & 7) << 4);                                     \
      gload16((const char*)Kg + (size_t)((s0) + r) * 128 + swz,                 \
              (char*)Ks[buf] + rb * 128);                                       \
    }                                                                           \
  }

  const int ksw = (l31 & 7) << 4;    // swizzle for K rows (l31)

  // one 64-row KV sub-tile at kv base s0v: V loads issued FIRST (global,
  // independent) -> QKT -> softmax -> PV consumes V regs.
#define PROCESS(sb, s0v)                                                        \
  {                                                                             \
    half8 vf[2][4];                                                             \
    _Pragma("unroll")                                                           \
    for (int cc = 0; cc < 2; ++cc)                                              \
      _Pragma("unroll")                                                         \
      for (int t4 = 0; t4 < 4; ++t4)                                            \
        vf[cc][t4] = *(const half8*)((const char*)Vg +                          \
            (size_t)(32 * cc + l31) * 4096 + (size_t)(s0v) * 2 +                \
            32 * t4 + 16 * hh);                                                 \
    f32x16 sacc[2];                                                             \
    _Pragma("unroll")                                                           \
    for (int s = 0; s < 2; ++s)                                                 \
      _Pragma("unroll")                                                         \
      for (int r = 0; r < 16; ++r) sacc[s][r] = 0.f;                            \
    _Pragma("unroll")                                                           \
    for (int s = 0; s < 2; ++s) {                                               \
      const int krow = 32 * s + l31;                                            \
      _Pragma("unroll")                                                         \
      for (int t4 = 0; t4 < 4; ++t4) {                                          \
        half8 kf = *(const half8*)((const char*)Ks[sb] + krow * 128 +           \
                                   ((32 * t4 + 16 * hh) ^ ksw));                \
        sacc[s] = __builtin_amdgcn_mfma_f32_32x32x16_f16(kf, qf[t4], sacc[s],   \
                                                         0, 0, 0);              \
      }                                                                         \
    }                                                                           \
    half8 pa[4];                                                                \
    _Pragma("unroll")                                                           \
    for (int s = 0; s < 2; ++s) {                                               \
      unsigned wpk[8];                                                          \
      _Pragma("unroll")                                                         \
      for (int i = 0; i < 8; ++i) {                                             \
        const float p0 = __ocml_native_exp2_f32(sacc[s][2 * i]);                \
        const float p1 = __ocml_native_exp2_f32(sacc[s][2 * i + 1]);            \
        const auto pk = __builtin_amdgcn_cvt_pkrtz(p0, p1);                     \
        __builtin_memcpy(&wpk[i], &pk, 4);                                      \
      }                                                                         \
      const auto r0 = __builtin_amdgcn_permlane32_swap(wpk[0], wpk[2], false, false); \
      const auto r1 = __builtin_amdgcn_permlane32_swap(wpk[1], wpk[3], false, false); \
      const auto r2 = __builtin_amdgcn_permlane32_swap(wpk[4], wpk[6], false, false); \
      const auto r3 = __builtin_amdgcn_permlane32_swap(wpk[5], wpk[7], false, false); \
      union { unsigned u[4]; half8 v; } lo, hi;                                 \
      lo.u[0] = r0[0]; lo.u[1] = r1[0]; lo.u[2] = r0[1]; lo.u[3] = r1[1];       \
      hi.u[0] = r2[0]; hi.u[1] = r3[0]; hi.u[2] = r2[1]; hi.u[3] = r3[1];       \
      pa[2 * s] = lo.v;                                                         \
      pa[2 * s + 1] = hi.v;                                                     \
    }                                                                           \
    _Pragma("unroll")                                                           \
    for (int t4 = 0; t4 < 4; ++t4) {                                            \
      lacc = __builtin_amdgcn_mfma_f32_32x32x16_f16(pa[t4], onesf, lacc, 0, 0, 0); \
      _Pragma("unroll")                                                         \
      for (int cc = 0; cc < 2; ++cc)                                            \
        oacc[cc] = __builtin_amdgcn_mfma_f32_32x32x16_f16(pa[t4], vf[cc][t4],   \
                                                          oacc[cc], 0, 0, 0);   \
    }                                                                           \
  }

  // prologue: logical buffer 0 = sub-buffers {0,1} = kv tiles 0,1
  STAGE(0, 0);
  STAGE(64, 1);
  asm volatile("s_waitcnt vmcnt(0)" ::: "memory");
  __builtin_amdgcn_s_barrier();

  for (int it = 0; it < 16; ++it) {
    const int base = (it & 1) << 1;          // sub-buffers {base, base+1}
    const int sbase = (base ^ 2);            // staging pair
    if (it < 15) {
      STAGE((2 * it + 2) * 64, sbase);
      STAGE((2 * it + 3) * 64, sbase + 1);
    }
    PROCESS(base, (2 * it) * 64);
    PROCESS(base + 1, (2 * it + 1) * 64);
    if (it < 15) {
      asm volatile("s_waitcnt vmcnt(0)" ::: "memory");
      __builtin_amdgcn_s_barrier();
    }
  }
#undef PROCESS
#undef STAGE

  // ---- normalize + store: oacc[cc][reg] = O[q=(reg&3)+8(reg>>2)+4hh][c=32cc+l31]
  const int bb = bh >> 4, hd = bh & 15;
#pragma unroll
  for (int reg = 0; reg < 16; ++reg) {
    const int q = qblk + w * 32 + (reg & 3) + 8 * (reg >> 2) + 4 * hh;
    const float ir = 1.0f / lacc[reg];
    const size_t base = ((size_t)bb * 2048 + q) * 1024 + hd * 64;
    AO[base + l31]      = (_Float16)(oacc[0][reg] * ir);
    AO[base + 32 + l31] = (_Float16)(oacc[1][reg] * ir);
  }
}

// ------------------------------------------------------- GEMM2: out proj
// 64x128 tile (grid 64x8 = 512 blocks = 2 blocks/CU).
__global__ __launch_bounds__(256) void gemm_out(
    const _Float16* __restrict__ AO, const _Float16* __restrict__ Wot,
    const float* __restrict__ bo, float* __restrict__ out)
{
  __shared__ __align__(16) _Float16 As[64 * 64], Bs[128 * 64];
  const int row0 = blockIdx.x * 64, col0 = blockIdx.y * 128;
  const int t = threadIdx.x, l = t & 63, l15 = l & 15, lg = l >> 4, w = t >> 6;
  const int wr = (w >> 1) * 32, wc = (w & 1) * 64;
  const int lsub = l >> 3, lcb = (l & 7) * 16;
  f32x4 acc[2][4];
#pragma unroll
  for (int m = 0; m < 2; ++m)
#pragma unroll
    for (int n = 0; n < 4; ++n)
      acc[m][n] = (f32x4){0.f, 0.f, 0.f, 0.f};

  for (int k0 = 0; k0 < 1024; k0 += 64) {
    __syncthreads();
#pragma unroll
    for (int i = 0; i < 2; ++i) {
      const int rb = w * 16 + i * 8;
      const int r = rb + lsub;
      const int swz = lcb ^ ((r & 7) << 4);
      gload16((const char*)AO + (size_t)(row0 + r) * 2048 + (size_t)k0 * 2 + swz,
              (char*)As + rb * 128);
    }
#pragma unroll
    for (int i = 0; i < 4; ++i) {
      const int rb = i * 32 + w * 8;
      const int r = rb + lsub;
      const int swz = lcb ^ ((r & 7) << 4);
      gload16((const char*)Wot + (size_t)(col0 + r) * 2048 + (size_t)k0 * 2 + swz,
              (char*)Bs + rb * 128);
    }
    __syncthreads();
#pragma unroll
    for (int kk = 0; kk < 2; ++kk) {
      const int kb = kk * 64 + (lg << 4);
      half8 af[2], bf[4];
#pragma unroll
      for (int m = 0; m < 2; ++m) {
        const int row = wr + 16 * m + l15;
        af[m] = *(const half8*)((const char*)As + row * 128 + (kb ^ ((row & 7) << 4)));
      }
#pragma unroll
      for (int n = 0; n < 4; ++n) {
        const int col = wc + 16 * n + l15;
        bf[n] = *(const half8*)((const char*)Bs + col * 128 + (kb ^ ((col & 7) << 4)));
      }
#pragma unroll
      for (int m = 0; m < 2; ++m)
#pragma unroll
        for (int n = 0; n < 4; ++n)
          acc[m][n] = __builtin_amdgcn_mfma_f32_16x16x32_f16(af[m], bf[n], acc[m][n], 0, 0, 0);
    }
  }

  const int wrow = row0 + wr, wcol = col0 + wc;
  float b[4];
#pragma unroll
  for (int n = 0; n < 4; ++n) b[n] = bo[wcol + 16 * n + l15];
#pragma unroll
  for (int m = 0; m < 2; ++m)
#pragma unroll
    for (int reg = 0; reg < 4; ++reg) {
      const int row = wrow + 16 * m + lg * 4 + reg;
#pragma unroll
      for (int n = 0; n < 4; ++n)
        out[(size_t)row * 1024 + wcol + 16 * n + l15] = acc[m][n][reg] + b[n];
    }
}

// ---------------------------------------------------------------- launch
extern "C" void kernel_launch(void* const* d_in, const int* in_sizes, int n_in,
                              void* d_out, int out_size, void* d_ws, size_t ws_size,
                              hipStream_t stream)
{
  const float* x   = (const float*)d_in[0];
  const float* Wq  = (const float*)d_in[1];
  const float* bq  = (const float*)d_in[2];
  const float* Wkv = (const float*)d_in[3];
  const float* bkv = (const float*)d_in[4];
  const float* Wo  = (const float*)d_in[5];
  const float* bo  = (const float*)d_in[6];
  float* out = (float*)d_out;
  char* ws = (char*)d_ws;

  _Float16* xb  = (_Float16*)(ws);
  _Float16* Wt  = (_Float16*)(ws + 8388608);
  _Float16* Wot = (_Float16*)(ws + 14680064);
  float2*   cs  = (float2*)  (ws + 16777216);
  _Float16* Qb  = (_Float16*)(ws + 17301504);
  _Float16* Kb  = (_Float16*)(ws + 25690112);
  _Float16* Vt  = (_Float16*)(ws + 34078720);
  _Float16* AO  = (_Float16*)(ws + 42467328);

  prep_kernel<<<6400, 256, 0, stream>>>(x, Wq, Wkv, Wo, xb, Wt, Wot, cs);
  gemm_qkv<<<dim3(32, 24), 256, 0, stream>>>(xb, Wt, bq, bkv, cs, Qb, Kb, Vt);
  attn_kernel<<<dim3(16, 32), 256, 0, stream>>>(Qb, Kb, Vt, AO);
  gemm_out<<<dim3(64, 8), 256, 0, stream>>>(AO, Wot, bo, out);
}

// Round 22
// 114.079 us; speedup vs baseline: 1.1866x; 1.1866x over previous
//
#include <hip/hip_runtime.h>
#include <hip/hip_bf16.h>
#include <math.h>

// Problem: B=2, T=2048, D=1024, H=16, C=64. fp32 in/out, fp16 MFMA internally.
//
// Workspace layout (bytes):
//   xb  @ 0         : x as fp16            (4096x1024)   8388608
//   Wt  @ 8388608   : [Wq;Wkv]^T fp16      (3072x1024)   6291456
//   Wot @ 14680064  : Wo^T fp16            (1024x1024)   2097152
//   cs  @ 16777216  : cos/sin table float2 (2048x32)      524288
//   Qb  @ 17301504  : Q roped*scale fp16 [B][H][T][C]    8388608
//   Kb  @ 25690112  : K roped fp16 [B][H][T][C]          8388608
//   Vt  @ 34078720  : V fp16 [B][H][C][T] (transposed)   8388608
//   AO  @ 42467328  : attention out fp16 [B*T][H*C]      8388608
//
// FINAL (r22 = r18/r20 config, best measured 114.09 us):
//  - r21 lesson: V "zero LDS reuse" direct-global loads regressed 51->77us;
//    global_load_lds is VGPR-free fire-and-forget DMA, the LDS round-trip IS
//    the cheap path. Reverted.
//  - r19 lesson: default x-first dispatch already near-optimal L2 for the
//    GEMMs; XCD row-chunking + attn setprio both regressed. Reverted.

typedef _Float16 half8 __attribute__((ext_vector_type(8)));
typedef _Float16 half4 __attribute__((ext_vector_type(4)));
typedef float f32x4 __attribute__((ext_vector_type(4)));
typedef float f32x16 __attribute__((ext_vector_type(16)));

// OCML native exp2 = raw v_exp_f32, compiler-visible (r16: libm exp2f's
// fixup tail was ~18% of attn VALU; builtin permlane closed the r13/r15
// inline-asm hazard).
extern "C" __device__ float __ocml_native_exp2_f32(float);

__device__ __forceinline__ void gload16(const void* g, void* l) {
  __builtin_amdgcn_global_load_lds(
      (const __attribute__((address_space(1))) void*)g,
      (__attribute__((address_space(3))) void*)l, 16, 0, 0);
}

// ---------------------------------------------------------------- prep
__global__ __launch_bounds__(256) void prep_kernel(
    const float* __restrict__ x, const float* __restrict__ Wq,
    const float* __restrict__ Wkv, const float* __restrict__ Wo,
    _Float16* __restrict__ xb, _Float16* __restrict__ Wt,
    _Float16* __restrict__ Wot, float2* __restrict__ cs)
{
  const int bid = blockIdx.x, t = threadIdx.x;
  if (bid < 2048) {
    size_t i = ((size_t)bid * 256 + t) * 8;
    const float4* p = (const float4*)(x + i);
    float4 a = p[0], b = p[1];
    half8 h;
    h[0] = (_Float16)a.x; h[1] = (_Float16)a.y; h[2] = (_Float16)a.z; h[3] = (_Float16)a.w;
    h[4] = (_Float16)b.x; h[5] = (_Float16)b.y; h[6] = (_Float16)b.z; h[7] = (_Float16)b.w;
    *(half8*)(xb + i) = h;
  } else if (bid < 6144) {
    int tt = bid - 2048;
    const float* src; _Float16* dst; int N, tk, tn;
    if (tt < 1024)      { src = Wq;  dst = Wt;                      N = 1024; tk = tt >> 5; tn = tt & 31; }
    else if (tt < 3072) { tt -= 1024; src = Wkv; dst = Wt + (size_t)1024 * 1024; N = 2048; tk = tt >> 6; tn = tt & 63; }
    else                { tt -= 3072; src = Wo;  dst = Wot;         N = 1024; tk = tt >> 5; tn = tt & 31; }
    __shared__ float tile[32][33];
    const int r = t >> 3, c4 = (t & 7) << 2;
    const float4 v = *(const float4*)(src + (size_t)(tk * 32 + r) * N + tn * 32 + c4);
    tile[r][c4 + 0] = v.x; tile[r][c4 + 1] = v.y; tile[r][c4 + 2] = v.z; tile[r][c4 + 3] = v.w;
    __syncthreads();
    half4 o;
    o[0] = (_Float16)tile[c4 + 0][r];
    o[1] = (_Float16)tile[c4 + 1][r];
    o[2] = (_Float16)tile[c4 + 2][r];
    o[3] = (_Float16)tile[c4 + 3][r];
    *(half4*)(dst + (size_t)(tn * 32 + r) * 1024 + tk * 32 + c4) = o;
  } else {
    int idx = (bid - 6144) * 256 + t;
    int tt = idx >> 5, j = idx & 31;
    float p = powf(10000.0f, (float)(2 * j) * (1.0f / 64.0f));
    float ang = (float)tt / p;
    float sn, cn;
    sincosf(ang, &sn, &cn);
    cs[idx] = make_float2(cn, sn);
  }
}

// ------------------------------------------------------------ GEMM core
__device__ __forceinline__ void gemm_core(
    const _Float16* __restrict__ A, const _Float16* __restrict__ B,
    _Float16* __restrict__ As, _Float16* __restrict__ Bs,
    int row0, int col0, f32x4 (&acc)[4][4])
{
  const int t = threadIdx.x;
  const int l = t & 63;
  const int l15 = l & 15, lg = l >> 4;
  const int w = t >> 6;
  const int wr = (w >> 1) * 64, wc = (w & 1) * 64;
#pragma unroll
  for (int m = 0; m < 4; ++m)
#pragma unroll
    for (int n = 0; n < 4; ++n)
      acc[m][n] = (f32x4){0.f, 0.f, 0.f, 0.f};

  const int lsub = l >> 3;
  const int lcb  = (l & 7) * 16;

  for (int k0 = 0; k0 < 1024; k0 += 64) {
    __syncthreads();
#pragma unroll
    for (int i = 0; i < 4; ++i) {
      const int rb = i * 32 + w * 8;
      const int r = rb + lsub;
      const int swz = lcb ^ ((r & 7) << 4);
      gload16((const char*)A + (size_t)(row0 + r) * 2048 + (size_t)k0 * 2 + swz,
              (char*)As + rb * 128);
      gload16((const char*)B + (size_t)(col0 + r) * 2048 + (size_t)k0 * 2 + swz,
              (char*)Bs + rb * 128);
    }
    __syncthreads();
#pragma unroll
    for (int kk = 0; kk < 2; ++kk) {
      const int kb = kk * 64 + (lg << 4);
      half8 af[4], bf[4];
#pragma unroll
      for (int m = 0; m < 4; ++m) {
        const int row = wr + 16 * m + l15;
        af[m] = *(const half8*)((const char*)As + row * 128 + (kb ^ ((row & 7) << 4)));
      }
#pragma unroll
      for (int n = 0; n < 4; ++n) {
        const int col = wc + 16 * n + l15;
        bf[n] = *(const half8*)((const char*)Bs + col * 128 + (kb ^ ((col & 7) << 4)));
      }
#pragma unroll
      for (int m = 0; m < 4; ++m)
#pragma unroll
        for (int n = 0; n < 4; ++n)
          acc[m][n] = __builtin_amdgcn_mfma_f32_16x16x32_f16(af[m], bf[n], acc[m][n], 0, 0, 0);
    }
  }
}

// ------------------------------------------------------- GEMM1: QKV+RoPE
// Q pre-scaled by (1/sqrt(C))*log2(e). V blocks (col0g >= 2048) computed
// TRANSPOSED (gemm_core with A/B swapped) so Vt[c][t] stores are contiguous
// in t instead of a per-lane 2B scatter (r17: part of the -5.3us GEMM win).
__global__ __launch_bounds__(256) void gemm_qkv(
    const _Float16* __restrict__ xb, const _Float16* __restrict__ Wt,
    const float* __restrict__ bq, const float* __restrict__ bkv,
    const float2* __restrict__ cs,
    _Float16* __restrict__ Qb, _Float16* __restrict__ Kb, _Float16* __restrict__ Vt)
{
  __shared__ __align__(16) _Float16 As[128 * 64], Bs[128 * 64];
  f32x4 acc[4][4];
  const int row0 = blockIdx.x * 128, col0g = blockIdx.y * 128;
  const int t = threadIdx.x, l = t & 63, l15 = l & 15, lg = l >> 4, w = t >> 6;

  if (col0g < 2048) {
    gemm_core(xb, Wt, As, Bs, row0, col0g, acc);
    const int wrow = row0 + (w >> 1) * 64;
    const int ncol = col0g + (w & 1) * 64;
    const int seg = ncol >> 10;              // 0:q 1:k
    const int hcol = ncol & 1023;
    const int h = hcol >> 6;
    const float* bias = (seg == 0) ? bq : bkv;
    _Float16* dst = (seg == 0) ? Qb : Kb;
    const float qs = (seg == 0) ? 0.18033688011112042f : 1.0f;  // sl2e or 1
    const float b0 = bias[hcol + l15],      b1 = bias[hcol + 16 + l15];
    const float b2 = bias[hcol + 32 + l15], b3 = bias[hcol + 48 + l15];
#pragma unroll
    for (int m = 0; m < 4; ++m) {
#pragma unroll
      for (int reg = 0; reg < 4; ++reg) {
        const int row = wrow + 16 * m + lg * 4 + reg;
        const int bb = row >> 11, tt = row & 2047;
        const float2 cs0 = cs[tt * 32 + l15];
        const float2 cs1 = cs[tt * 32 + 16 + l15];
        const float v0 = acc[m][0][reg] + b0;
        const float v1 = acc[m][1][reg] + b1;
        const float v2 = acc[m][2][reg] + b2;
        const float v3 = acc[m][3][reg] + b3;
        const size_t base = ((size_t)(bb * 16 + h) * 2048 + tt) * 64;
        dst[base + l15]      = (_Float16)((v0 * cs0.x - v2 * cs0.y) * qs);
        dst[base + 16 + l15] = (_Float16)((v1 * cs1.x - v3 * cs1.y) * qs);
        dst[base + 32 + l15] = (_Float16)((v2 * cs0.x + v0 * cs0.y) * qs);
        dst[base + 48 + l15] = (_Float16)((v3 * cs1.x + v1 * cs1.y) * qs);
      }
    }
  } else {
    gemm_core(Wt, xb, As, Bs, col0g, row0, acc);
    const int vcol = (col0g - 2048) + (w >> 1) * 64;   // wave's base v-channel
    const int tbase = row0 + (w & 1) * 64;             // wave's base t
#pragma unroll
    for (int m = 0; m < 4; ++m) {
#pragma unroll
      for (int reg = 0; reg < 4; ++reg) {
        const int vchan = vcol + 16 * m + lg * 4 + reg;      // 0..1023
        const float bv = bkv[1024 + vchan];
        const size_t crow = (size_t)(vchan >> 6) * 64 + (vchan & 63);
#pragma unroll
        for (int n = 0; n < 4; ++n) {
          const int tg = tbase + 16 * n + l15;
          const int bb2 = tg >> 11, tt2 = tg & 2047;
          Vt[((size_t)bb2 * 1024 + crow) * 2048 + tt2] =
              (_Float16)(acc[m][n][reg] + bv);
        }
      }
    }
  }
}

// ------------------------------------------------------- flash attention
// r16 body + KVBLK=128: two 64-row KV sub-tiles per barrier region.
// 4 sub-buffers = 2 logical double-buffers (64 KB LDS, 2 blocks/CU).
// Barrier pairs halve (31 -> 15) and sub-tile B's QKT is independent of
// sub-tile A's softmax/PV, so the scheduler gets cross-subtile ILP inside
// each barrier-free region. End-of-region vmcnt(0) is near-free: staging
// loads get a full 2-subtile compute (~4000 cyc) to land.
__global__ __launch_bounds__(256, 2) void attn_kernel(
    const _Float16* __restrict__ Qb, const _Float16* __restrict__ Kb,
    const _Float16* __restrict__ Vt, _Float16* __restrict__ AO)
{
  __shared__ __align__(16) _Float16 Ks[4][64 * 64], Vs[4][64 * 64];   // 64 KB
  // bijective swizzle of 512 blocks: 8 XCDs x (4 bh x 16 qtiles)
  const int lin = blockIdx.x + (blockIdx.y << 4);
  const int xcd = lin & 7, idx = lin >> 3;          // idx 0..63
  const int bh = (xcd << 2) + (idx >> 4);
  const int qblk = (idx & 15) << 7;                 // 128 q rows per block
  const int t = threadIdx.x, l = t & 63, l31 = l & 31, hh = l >> 5, w = t >> 6;
  const _Float16* Qg = Qb + (size_t)bh * 2048 * 64;
  const _Float16* Kg = Kb + (size_t)bh * 2048 * 64;
  const _Float16* Vg = Vt + (size_t)bh * 64 * 2048;

  // Q fragments (B operand, 32x32x16): col=q=l31, k(c) = 32*t4 + 16*hh + j
  const int qrow = qblk + w * 32 + l31;
  half8 qf[4];
#pragma unroll
  for (int t4 = 0; t4 < 4; ++t4)
    qf[t4] = *(const half8*)((const char*)Qg + (size_t)qrow * 128 + t4 * 32 + hh * 16);

  f32x16 oacc[2], lacc;
#pragma unroll
  for (int cc = 0; cc < 2; ++cc)
#pragma unroll
    for (int r = 0; r < 16; ++r) oacc[cc][r] = 0.f;
#pragma unroll
  for (int r = 0; r < 16; ++r) lacc[r] = 0.f;
  const half8 onesf = {(_Float16)1, (_Float16)1, (_Float16)1, (_Float16)1,
                       (_Float16)1, (_Float16)1, (_Float16)1, (_Float16)1};

  const int lsub = l >> 3;
  const int lcb  = (l & 7) * 16;

#define STAGE(s0, buf)                                                          \
  {                                                                             \
    _Pragma("unroll")                                                           \
    for (int i = 0; i < 2; ++i) {                                               \
      const int rb = w * 16 + i * 8;                                            \
      const int r = rb + lsub;                                                  \
      const int swz = lcb ^ ((r & 7) << 4);                                     \
      gload16((const char*)Kg + (size_t)((s0) + r) * 128 + swz,                 \
              (char*)Ks[buf] + rb * 128);                                       \
      gload16((const char*)Vg + (size_t)r * 4096 + (size_t)(s0) * 2 + swz,      \
              (char*)Vs[buf] + rb * 128);                                       \
    }                                                                           \
  }

  const int ksw = (l31 & 7) << 4;    // swizzle for K rows (l31) and V rows

  // one 64-row KV sub-tile: QKT -> softmax (native exp2, builtin permlane)
  // -> PV + ones-column row sums
#define PROCESS(sb)                                                             \
  {                                                                             \
    f32x16 sacc[2];                                                             \
    _Pragma("unroll")                                                           \
    for (int s = 0; s < 2; ++s)                                                 \
      _Pragma("unroll")                                                         \
      for (int r = 0; r < 16; ++r) sacc[s][r] = 0.f;                            \
    _Pragma("unroll")                                                           \
    for (int s = 0; s < 2; ++s) {                                               \
      const int krow = 32 * s + l31;                                            \
      _Pragma("unroll")                                                         \
      for (int t4 = 0; t4 < 4; ++t4) {                                          \
        half8 kf = *(const half8*)((const char*)Ks[sb] + krow * 128 +           \
                                   ((32 * t4 + 16 * hh) ^ ksw));                \
        sacc[s] = __builtin_amdgcn_mfma_f32_32x32x16_f16(kf, qf[t4], sacc[s],   \
                                                         0, 0, 0);              \
      }                                                                         \
    }                                                                           \
    half8 pa[4];                                                                \
    _Pragma("unroll")                                                           \
    for (int s = 0; s < 2; ++s) {                                               \
      unsigned wpk[8];                                                          \
      _Pragma("unroll")                                                         \
      for (int i = 0; i < 8; ++i) {                                             \
        const float p0 = __ocml_native_exp2_f32(sacc[s][2 * i]);                \
        const float p1 = __ocml_native_exp2_f32(sacc[s][2 * i + 1]);            \
        const auto pk = __builtin_amdgcn_cvt_pkrtz(p0, p1);                     \
        __builtin_memcpy(&wpk[i], &pk, 4);                                      \
      }                                                                         \
      const auto r0 = __builtin_amdgcn_permlane32_swap(wpk[0], wpk[2], false, false); \
      const auto r1 = __builtin_amdgcn_permlane32_swap(wpk[1], wpk[3], false, false); \
      const auto r2 = __builtin_amdgcn_permlane32_swap(wpk[4], wpk[6], false, false); \
      const auto r3 = __builtin_amdgcn_permlane32_swap(wpk[5], wpk[7], false, false); \
      union { unsigned u[4]; half8 v; } lo, hi;                                 \
      lo.u[0] = r0[0]; lo.u[1] = r1[0]; lo.u[2] = r0[1]; lo.u[3] = r1[1];       \
      hi.u[0] = r2[0]; hi.u[1] = r3[0]; hi.u[2] = r2[1]; hi.u[3] = r3[1];       \
      pa[2 * s] = lo.v;                                                         \
      pa[2 * s + 1] = hi.v;                                                     \
    }                                                                           \
    _Pragma("unroll")                                                           \
    for (int t4 = 0; t4 < 4; ++t4) {                                            \
      lacc = __builtin_amdgcn_mfma_f32_32x32x16_f16(pa[t4], onesf, lacc, 0, 0, 0); \
      _Pragma("unroll")                                                         \
      for (int cc = 0; cc < 2; ++cc) {                                          \
        const int vrow = 32 * cc + l31;                                         \
        half8 vf = *(const half8*)((const char*)Vs[sb] + vrow * 128 +           \
                                   ((32 * t4 + 16 * hh) ^ ksw));                \
        oacc[cc] = __builtin_amdgcn_mfma_f32_32x32x16_f16(pa[t4], vf, oacc[cc], \
                                                          0, 0, 0);             \
      }                                                                         \
    }                                                                           \
  }

  // prologue: logical buffer 0 = sub-buffers {0,1} = kv tiles 0,1
  STAGE(0, 0);
  STAGE(64, 1);
  asm volatile("s_waitcnt vmcnt(0)" ::: "memory");
  __builtin_amdgcn_s_barrier();

  for (int it = 0; it < 16; ++it) {
    const int base = (it & 1) << 1;          // sub-buffers {base, base+1}
    const int sbase = (base ^ 2);            // staging pair
    if (it < 15) {
      STAGE((2 * it + 2) * 64, sbase);
      STAGE((2 * it + 3) * 64, sbase + 1);
    }
    PROCESS(base);
    PROCESS(base + 1);
    if (it < 15) {
      asm volatile("s_waitcnt vmcnt(0)" ::: "memory");
      __builtin_amdgcn_s_barrier();
    }
  }
#undef PROCESS
#undef STAGE

  // ---- normalize + store: oacc[cc][reg] = O[q=(reg&3)+8(reg>>2)+4hh][c=32cc+l31]
  const int bb = bh >> 4, hd = bh & 15;
#pragma unroll
  for (int reg = 0; reg < 16; ++reg) {
    const int q = qblk + w * 32 + (reg & 3) + 8 * (reg >> 2) + 4 * hh;
    const float ir = 1.0f / lacc[reg];
    const size_t base = ((size_t)bb * 2048 + q) * 1024 + hd * 64;
    AO[base + l31]      = (_Float16)(oacc[0][reg] * ir);
    AO[base + 32 + l31] = (_Float16)(oacc[1][reg] * ir);
  }
}

// ------------------------------------------------------- GEMM2: out proj
// 64x128 tile (grid 64x8 = 512 blocks = 2 blocks/CU).
__global__ __launch_bounds__(256) void gemm_out(
    const _Float16* __restrict__ AO, const _Float16* __restrict__ Wot,
    const float* __restrict__ bo, float* __restrict__ out)
{
  __shared__ __align__(16) _Float16 As[64 * 64], Bs[128 * 64];
  const int row0 = blockIdx.x * 64, col0 = blockIdx.y * 128;
  const int t = threadIdx.x, l = t & 63, l15 = l & 15, lg = l >> 4, w = t >> 6;
  const int wr = (w >> 1) * 32, wc = (w & 1) * 64;
  const int lsub = l >> 3, lcb = (l & 7) * 16;
  f32x4 acc[2][4];
#pragma unroll
  for (int m = 0; m < 2; ++m)
#pragma unroll
    for (int n = 0; n < 4; ++n)
      acc[m][n] = (f32x4){0.f, 0.f, 0.f, 0.f};

  for (int k0 = 0; k0 < 1024; k0 += 64) {
    __syncthreads();
#pragma unroll
    for (int i = 0; i < 2; ++i) {
      const int rb = w * 16 + i * 8;
      const int r = rb + lsub;
      const int swz = lcb ^ ((r & 7) << 4);
      gload16((const char*)AO + (size_t)(row0 + r) * 2048 + (size_t)k0 * 2 + swz,
              (char*)As + rb * 128);
    }
#pragma unroll
    for (int i = 0; i < 4; ++i) {
      const int rb = i * 32 + w * 8;
      const int r = rb + lsub;
      const int swz = lcb ^ ((r & 7) << 4);
      gload16((const char*)Wot + (size_t)(col0 + r) * 2048 + (size_t)k0 * 2 + swz,
              (char*)Bs + rb * 128);
    }
    __syncthreads();
#pragma unroll
    for (int kk = 0; kk < 2; ++kk) {
      const int kb = kk * 64 + (lg << 4);
      half8 af[2], bf[4];
#pragma unroll
      for (int m = 0; m < 2; ++m) {
        const int row = wr + 16 * m + l15;
        af[m] = *(const half8*)((const char*)As + row * 128 + (kb ^ ((row & 7) << 4)));
      }
#pragma unroll
      for (int n = 0; n < 4; ++n) {
        const int col = wc + 16 * n + l15;
        bf[n] = *(const half8*)((const char*)Bs + col * 128 + (kb ^ ((col & 7) << 4)));
      }
#pragma unroll
      for (int m = 0; m < 2; ++m)
#pragma unroll
        for (int n = 0; n < 4; ++n)
          acc[m][n] = __builtin_amdgcn_mfma_f32_16x16x32_f16(af[m], bf[n], acc[m][n], 0, 0, 0);
    }
  }

  const int wrow = row0 + wr, wcol = col0 + wc;
  float b[4];
#pragma unroll
  for (int n = 0; n < 4; ++n) b[n] = bo[wcol + 16 * n + l15];
#pragma unroll
  for (int m = 0; m < 2; ++m)
#pragma unroll
    for (int reg = 0; reg < 4; ++reg) {
      const int row = wrow + 16 * m + lg * 4 + reg;
#pragma unroll
      for (int n = 0; n < 4; ++n)
        out[(size_t)row * 1024 + wcol + 16 * n + l15] = acc[m][n][reg] + b[n];
    }
}

// ---------------------------------------------------------------- launch
extern "C" void kernel_launch(void* const* d_in, const int* in_sizes, int n_in,
                              void* d_out, int out_size, void* d_ws, size_t ws_size,
                              hipStream_t stream)
{
  const float* x   = (const float*)d_in[0];
  const float* Wq  = (const float*)d_in[1];
  const float* bq  = (const float*)d_in[2];
  const float* Wkv = (const float*)d_in[3];
  const float* bkv = (const float*)d_in[4];
  const float* Wo  = (const float*)d_in[5];
  const float* bo  = (const float*)d_in[6];
  float* out = (float*)d_out;
  char* ws = (char*)d_ws;

  _Float16* xb  = (_Float16*)(ws);
  _Float16* Wt  = (_Float16*)(ws + 8388608);
  _Float16* Wot = (_Float16*)(ws + 14680064);
  float2*   cs  = (float2*)  (ws + 16777216);
  _Float16* Qb  = (_Float16*)(ws + 17301504);
  _Float16* Kb  = (_Float16*)(ws + 25690112);
  _Float16* Vt  = (_Float16*)(ws + 34078720);
  _Float16* AO  = (_Float16*)(ws + 42467328);

  prep_kernel<<<6400, 256, 0, stream>>>(x, Wq, Wkv, Wo, xb, Wt, Wot, cs);
  gemm_qkv<<<dim3(32, 24), 256, 0, stream>>>(xb, Wt, bq, bkv, cs, Qb, Kb, Vt);
  attn_kernel<<<dim3(16, 32), 256, 0, stream>>>(Qb, Kb, Vt, AO);
  gemm_out<<<dim3(64, 8), 256, 0, stream>>>(AO, Wot, bo, out);
}

// Round 23
// 113.254 us; speedup vs baseline: 1.1953x; 1.0073x over previous
//
#include <hip/hip_runtime.h>
#include <hip/hip_bf16.h>
#include <math.h>

// Problem: B=2, T=2048, D=1024, H=16, C=64. fp32 in/out, fp16 MFMA internally.
//
// Workspace layout (bytes):
//   xb  @ 0         : x as fp16            (4096x1024)   8388608
//   Wt  @ 8388608   : [Wq;Wkv]^T fp16      (3072x1024)   6291456
//   Wot @ 14680064  : Wo^T fp16            (1024x1024)   2097152
//   cs  @ 16777216  : cos/sin table float2 (2048x32)      524288
//   Qb  @ 17301504  : Q roped*scale fp16 [B][H][T][C]    8388608
//   Kb  @ 25690112  : K roped fp16 [B][H][T][C]          8388608
//   Vt  @ 34078720  : V fp16 [B][H][C][T] (transposed)   8388608
//   AO  @ 42467328  : attention out fp16 [B*T][H*C]      8388608
//
// r22 banked config + r23: gemm_out tile 64x128 -> 64x64 (grid 1024 = 4
// blocks/CU = 4 waves/SIMD, doubling TLP over the drained staging loop).
// Ledger: r21 V-direct regressed (gload_lds is VGPR-free DMA -- LDS
// round-trip IS the cheap path); r19 XCD-chunked GEMMs + attn setprio
// regressed; r18 KVBLK=128 (+6%), r16 native exp2 + builtin permlane
// (attn 71->54), r17 V-transposed epilogue + gemm_out 64-row tiles.

typedef _Float16 half8 __attribute__((ext_vector_type(8)));
typedef _Float16 half4 __attribute__((ext_vector_type(4)));
typedef float f32x4 __attribute__((ext_vector_type(4)));
typedef float f32x16 __attribute__((ext_vector_type(16)));

// OCML native exp2 = raw v_exp_f32, compiler-visible (r16: libm exp2f's
// fixup tail was ~18% of attn VALU; builtin permlane closed the r13/r15
// inline-asm hazard).
extern "C" __device__ float __ocml_native_exp2_f32(float);

__device__ __forceinline__ void gload16(const void* g, void* l) {
  __builtin_amdgcn_global_load_lds(
      (const __attribute__((address_space(1))) void*)g,
      (__attribute__((address_space(3))) void*)l, 16, 0, 0);
}

// ---------------------------------------------------------------- prep
__global__ __launch_bounds__(256) void prep_kernel(
    const float* __restrict__ x, const float* __restrict__ Wq,
    const float* __restrict__ Wkv, const float* __restrict__ Wo,
    _Float16* __restrict__ xb, _Float16* __restrict__ Wt,
    _Float16* __restrict__ Wot, float2* __restrict__ cs)
{
  const int bid = blockIdx.x, t = threadIdx.x;
  if (bid < 2048) {
    size_t i = ((size_t)bid * 256 + t) * 8;
    const float4* p = (const float4*)(x + i);
    float4 a = p[0], b = p[1];
    half8 h;
    h[0] = (_Float16)a.x; h[1] = (_Float16)a.y; h[2] = (_Float16)a.z; h[3] = (_Float16)a.w;
    h[4] = (_Float16)b.x; h[5] = (_Float16)b.y; h[6] = (_Float16)b.z; h[7] = (_Float16)b.w;
    *(half8*)(xb + i) = h;
  } else if (bid < 6144) {
    int tt = bid - 2048;
    const float* src; _Float16* dst; int N, tk, tn;
    if (tt < 1024)      { src = Wq;  dst = Wt;                      N = 1024; tk = tt >> 5; tn = tt & 31; }
    else if (tt < 3072) { tt -= 1024; src = Wkv; dst = Wt + (size_t)1024 * 1024; N = 2048; tk = tt >> 6; tn = tt & 63; }
    else                { tt -= 3072; src = Wo;  dst = Wot;         N = 1024; tk = tt >> 5; tn = tt & 31; }
    __shared__ float tile[32][33];
    const int r = t >> 3, c4 = (t & 7) << 2;
    const float4 v = *(const float4*)(src + (size_t)(tk * 32 + r) * N + tn * 32 + c4);
    tile[r][c4 + 0] = v.x; tile[r][c4 + 1] = v.y; tile[r][c4 + 2] = v.z; tile[r][c4 + 3] = v.w;
    __syncthreads();
    half4 o;
    o[0] = (_Float16)tile[c4 + 0][r];
    o[1] = (_Float16)tile[c4 + 1][r];
    o[2] = (_Float16)tile[c4 + 2][r];
    o[3] = (_Float16)tile[c4 + 3][r];
    *(half4*)(dst + (size_t)(tn * 32 + r) * 1024 + tk * 32 + c4) = o;
  } else {
    int idx = (bid - 6144) * 256 + t;
    int tt = idx >> 5, j = idx & 31;
    float p = powf(10000.0f, (float)(2 * j) * (1.0f / 64.0f));
    float ang = (float)tt / p;
    float sn, cn;
    sincosf(ang, &sn, &cn);
    cs[idx] = make_float2(cn, sn);
  }
}

// ------------------------------------------------------------ GEMM core
__device__ __forceinline__ void gemm_core(
    const _Float16* __restrict__ A, const _Float16* __restrict__ B,
    _Float16* __restrict__ As, _Float16* __restrict__ Bs,
    int row0, int col0, f32x4 (&acc)[4][4])
{
  const int t = threadIdx.x;
  const int l = t & 63;
  const int l15 = l & 15, lg = l >> 4;
  const int w = t >> 6;
  const int wr = (w >> 1) * 64, wc = (w & 1) * 64;
#pragma unroll
  for (int m = 0; m < 4; ++m)
#pragma unroll
    for (int n = 0; n < 4; ++n)
      acc[m][n] = (f32x4){0.f, 0.f, 0.f, 0.f};

  const int lsub = l >> 3;
  const int lcb  = (l & 7) * 16;

  for (int k0 = 0; k0 < 1024; k0 += 64) {
    __syncthreads();
#pragma unroll
    for (int i = 0; i < 4; ++i) {
      const int rb = i * 32 + w * 8;
      const int r = rb + lsub;
      const int swz = lcb ^ ((r & 7) << 4);
      gload16((const char*)A + (size_t)(row0 + r) * 2048 + (size_t)k0 * 2 + swz,
              (char*)As + rb * 128);
      gload16((const char*)B + (size_t)(col0 + r) * 2048 + (size_t)k0 * 2 + swz,
              (char*)Bs + rb * 128);
    }
    __syncthreads();
#pragma unroll
    for (int kk = 0; kk < 2; ++kk) {
      const int kb = kk * 64 + (lg << 4);
      half8 af[4], bf[4];
#pragma unroll
      for (int m = 0; m < 4; ++m) {
        const int row = wr + 16 * m + l15;
        af[m] = *(const half8*)((const char*)As + row * 128 + (kb ^ ((row & 7) << 4)));
      }
#pragma unroll
      for (int n = 0; n < 4; ++n) {
        const int col = wc + 16 * n + l15;
        bf[n] = *(const half8*)((const char*)Bs + col * 128 + (kb ^ ((col & 7) << 4)));
      }
#pragma unroll
      for (int m = 0; m < 4; ++m)
#pragma unroll
        for (int n = 0; n < 4; ++n)
          acc[m][n] = __builtin_amdgcn_mfma_f32_16x16x32_f16(af[m], bf[n], acc[m][n], 0, 0, 0);
    }
  }
}

// ------------------------------------------------------- GEMM1: QKV+RoPE
// Q pre-scaled by (1/sqrt(C))*log2(e). V blocks (col0g >= 2048) computed
// TRANSPOSED (gemm_core with A/B swapped) so Vt[c][t] stores are contiguous
// in t instead of a per-lane 2B scatter (r17: part of the -5.3us GEMM win).
__global__ __launch_bounds__(256) void gemm_qkv(
    const _Float16* __restrict__ xb, const _Float16* __restrict__ Wt,
    const float* __restrict__ bq, const float* __restrict__ bkv,
    const float2* __restrict__ cs,
    _Float16* __restrict__ Qb, _Float16* __restrict__ Kb, _Float16* __restrict__ Vt)
{
  __shared__ __align__(16) _Float16 As[128 * 64], Bs[128 * 64];
  f32x4 acc[4][4];
  const int row0 = blockIdx.x * 128, col0g = blockIdx.y * 128;
  const int t = threadIdx.x, l = t & 63, l15 = l & 15, lg = l >> 4, w = t >> 6;

  if (col0g < 2048) {
    gemm_core(xb, Wt, As, Bs, row0, col0g, acc);
    const int wrow = row0 + (w >> 1) * 64;
    const int ncol = col0g + (w & 1) * 64;
    const int seg = ncol >> 10;              // 0:q 1:k
    const int hcol = ncol & 1023;
    const int h = hcol >> 6;
    const float* bias = (seg == 0) ? bq : bkv;
    _Float16* dst = (seg == 0) ? Qb : Kb;
    const float qs = (seg == 0) ? 0.18033688011112042f : 1.0f;  // sl2e or 1
    const float b0 = bias[hcol + l15],      b1 = bias[hcol + 16 + l15];
    const float b2 = bias[hcol + 32 + l15], b3 = bias[hcol + 48 + l15];
#pragma unroll
    for (int m = 0; m < 4; ++m) {
#pragma unroll
      for (int reg = 0; reg < 4; ++reg) {
        const int row = wrow + 16 * m + lg * 4 + reg;
        const int bb = row >> 11, tt = row & 2047;
        const float2 cs0 = cs[tt * 32 + l15];
        const float2 cs1 = cs[tt * 32 + 16 + l15];
        const float v0 = acc[m][0][reg] + b0;
        const float v1 = acc[m][1][reg] + b1;
        const float v2 = acc[m][2][reg] + b2;
        const float v3 = acc[m][3][reg] + b3;
        const size_t base = ((size_t)(bb * 16 + h) * 2048 + tt) * 64;
        dst[base + l15]      = (_Float16)((v0 * cs0.x - v2 * cs0.y) * qs);
        dst[base + 16 + l15] = (_Float16)((v1 * cs1.x - v3 * cs1.y) * qs);
        dst[base + 32 + l15] = (_Float16)((v2 * cs0.x + v0 * cs0.y) * qs);
        dst[base + 48 + l15] = (_Float16)((v3 * cs1.x + v1 * cs1.y) * qs);
      }
    }
  } else {
    gemm_core(Wt, xb, As, Bs, col0g, row0, acc);
    const int vcol = (col0g - 2048) + (w >> 1) * 64;   // wave's base v-channel
    const int tbase = row0 + (w & 1) * 64;             // wave's base t
#pragma unroll
    for (int m = 0; m < 4; ++m) {
#pragma unroll
      for (int reg = 0; reg < 4; ++reg) {
        const int vchan = vcol + 16 * m + lg * 4 + reg;      // 0..1023
        const float bv = bkv[1024 + vchan];
        const size_t crow = (size_t)(vchan >> 6) * 64 + (vchan & 63);
#pragma unroll
        for (int n = 0; n < 4; ++n) {
          const int tg = tbase + 16 * n + l15;
          const int bb2 = tg >> 11, tt2 = tg & 2047;
          Vt[((size_t)bb2 * 1024 + crow) * 2048 + tt2] =
              (_Float16)(acc[m][n][reg] + bv);
        }
      }
    }
  }
}

// ------------------------------------------------------- flash attention
// r16 body + KVBLK=128: two 64-row KV sub-tiles per barrier region.
// 4 sub-buffers = 2 logical double-buffers (64 KB LDS, 2 blocks/CU).
// Barrier pairs halve (31 -> 15) and sub-tile B's QKT is independent of
// sub-tile A's softmax/PV, so the scheduler gets cross-subtile ILP inside
// each barrier-free region. End-of-region vmcnt(0) is near-free: staging
// loads get a full 2-subtile compute (~4000 cyc) to land.
__global__ __launch_bounds__(256, 2) void attn_kernel(
    const _Float16* __restrict__ Qb, const _Float16* __restrict__ Kb,
    const _Float16* __restrict__ Vt, _Float16* __restrict__ AO)
{
  __shared__ __align__(16) _Float16 Ks[4][64 * 64], Vs[4][64 * 64];   // 64 KB
  // bijective swizzle of 512 blocks: 8 XCDs x (4 bh x 16 qtiles)
  const int lin = blockIdx.x + (blockIdx.y << 4);
  const int xcd = lin & 7, idx = lin >> 3;          // idx 0..63
  const int bh = (xcd << 2) + (idx >> 4);
  const int qblk = (idx & 15) << 7;                 // 128 q rows per block
  const int t = threadIdx.x, l = t & 63, l31 = l & 31, hh = l >> 5, w = t >> 6;
  const _Float16* Qg = Qb + (size_t)bh * 2048 * 64;
  const _Float16* Kg = Kb + (size_t)bh * 2048 * 64;
  const _Float16* Vg = Vt + (size_t)bh * 64 * 2048;

  // Q fragments (B operand, 32x32x16): col=q=l31, k(c) = 32*t4 + 16*hh + j
  const int qrow = qblk + w * 32 + l31;
  half8 qf[4];
#pragma unroll
  for (int t4 = 0; t4 < 4; ++t4)
    qf[t4] = *(const half8*)((const char*)Qg + (size_t)qrow * 128 + t4 * 32 + hh * 16);

  f32x16 oacc[2], lacc;
#pragma unroll
  for (int cc = 0; cc < 2; ++cc)
#pragma unroll
    for (int r = 0; r < 16; ++r) oacc[cc][r] = 0.f;
#pragma unroll
  for (int r = 0; r < 16; ++r) lacc[r] = 0.f;
  const half8 onesf = {(_Float16)1, (_Float16)1, (_Float16)1, (_Float16)1,
                       (_Float16)1, (_Float16)1, (_Float16)1, (_Float16)1};

  const int lsub = l >> 3;
  const int lcb  = (l & 7) * 16;

#define STAGE(s0, buf)                                                          \
  {                                                                             \
    _Pragma("unroll")                                                           \
    for (int i = 0; i < 2; ++i) {                                               \
      const int rb = w * 16 + i * 8;                                            \
      const int r = rb + lsub;                                                  \
      const int swz = lcb ^ ((r & 7) << 4);                                     \
      gload16((const char*)Kg + (size_t)((s0) + r) * 128 + swz,                 \
              (char*)Ks[buf] + rb * 128);                                       \
      gload16((const char*)Vg + (size_t)r * 4096 + (size_t)(s0) * 2 + swz,      \
              (char*)Vs[buf] + rb * 128);                                       \
    }                                                                           \
  }

  const int ksw = (l31 & 7) << 4;    // swizzle for K rows (l31) and V rows

  // one 64-row KV sub-tile: QKT -> softmax (native exp2, builtin permlane)
  // -> PV + ones-column row sums
#define PROCESS(sb)                                                             \
  {                                                                             \
    f32x16 sacc[2];                                                             \
    _Pragma("unroll")                                                           \
    for (int s = 0; s < 2; ++s)                                                 \
      _Pragma("unroll")                                                         \
      for (int r = 0; r < 16; ++r) sacc[s][r] = 0.f;                            \
    _Pragma("unroll")                                                           \
    for (int s = 0; s < 2; ++s) {                                               \
      const int krow = 32 * s + l31;                                            \
      _Pragma("unroll")                                                         \
      for (int t4 = 0; t4 < 4; ++t4) {                                          \
        half8 kf = *(const half8*)((const char*)Ks[sb] + krow * 128 +           \
                                   ((32 * t4 + 16 * hh) ^ ksw));                \
        sacc[s] = __builtin_amdgcn_mfma_f32_32x32x16_f16(kf, qf[t4], sacc[s],   \
                                                         0, 0, 0);              \
      }                                                                         \
    }                                                                           \
    half8 pa[4];                                                                \
    _Pragma("unroll")                                                           \
    for (int s = 0; s < 2; ++s) {                                               \
      unsigned wpk[8];                                                          \
      _Pragma("unroll")                                                         \
      for (int i = 0; i < 8; ++i) {                                             \
        const float p0 = __ocml_native_exp2_f32(sacc[s][2 * i]);                \
        const float p1 = __ocml_native_exp2_f32(sacc[s][2 * i + 1]);            \
        const auto pk = __builtin_amdgcn_cvt_pkrtz(p0, p1);                     \
        __builtin_memcpy(&wpk[i], &pk, 4);                                      \
      }                                                                         \
      const auto r0 = __builtin_amdgcn_permlane32_swap(wpk[0], wpk[2], false, false); \
      const auto r1 = __builtin_amdgcn_permlane32_swap(wpk[1], wpk[3], false, false); \
      const auto r2 = __builtin_amdgcn_permlane32_swap(wpk[4], wpk[6], false, false); \
      const auto r3 = __builtin_amdgcn_permlane32_swap(wpk[5], wpk[7], false, false); \
      union { unsigned u[4]; half8 v; } lo, hi;                                 \
      lo.u[0] = r0[0]; lo.u[1] = r1[0]; lo.u[2] = r0[1]; lo.u[3] = r1[1];       \
      hi.u[0] = r2[0]; hi.u[1] = r3[0]; hi.u[2] = r2[1]; hi.u[3] = r3[1];       \
      pa[2 * s] = lo.v;                                                         \
      pa[2 * s + 1] = hi.v;                                                     \
    }                                                                           \
    _Pragma("unroll")                                                           \
    for (int t4 = 0; t4 < 4; ++t4) {                                            \
      lacc = __builtin_amdgcn_mfma_f32_32x32x16_f16(pa[t4], onesf, lacc, 0, 0, 0); \
      _Pragma("unroll")                                                         \
      for (int cc = 0; cc < 2; ++cc) {                                          \
        const int vrow = 32 * cc + l31;                                         \
        half8 vf = *(const half8*)((const char*)Vs[sb] + vrow * 128 +           \
                                   ((32 * t4 + 16 * hh) ^ ksw));                \
        oacc[cc] = __builtin_amdgcn_mfma_f32_32x32x16_f16(pa[t4], vf, oacc[cc], \
                                                          0, 0, 0);             \
      }                                                                         \
    }                                                                           \
  }

  // prologue: logical buffer 0 = sub-buffers {0,1} = kv tiles 0,1
  STAGE(0, 0);
  STAGE(64, 1);
  asm volatile("s_waitcnt vmcnt(0)" ::: "memory");
  __builtin_amdgcn_s_barrier();

  for (int it = 0; it < 16; ++it) {
    const int base = (it & 1) << 1;          // sub-buffers {base, base+1}
    const int sbase = (base ^ 2);            // staging pair
    if (it < 15) {
      STAGE((2 * it + 2) * 64, sbase);
      STAGE((2 * it + 3) * 64, sbase + 1);
    }
    PROCESS(base);
    PROCESS(base + 1);
    if (it < 15) {
      asm volatile("s_waitcnt vmcnt(0)" ::: "memory");
      __builtin_amdgcn_s_barrier();
    }
  }
#undef PROCESS
#undef STAGE

  // ---- normalize + store: oacc[cc][reg] = O[q=(reg&3)+8(reg>>2)+4hh][c=32cc+l31]
  const int bb = bh >> 4, hd = bh & 15;
#pragma unroll
  for (int reg = 0; reg < 16; ++reg) {
    const int q = qblk + w * 32 + (reg & 3) + 8 * (reg >> 2) + 4 * hh;
    const float ir = 1.0f / lacc[reg];
    const size_t base = ((size_t)bb * 2048 + q) * 1024 + hd * 64;
    AO[base + l31]      = (_Float16)(oacc[0][reg] * ir);
    AO[base + 32 + l31] = (_Float16)(oacc[1][reg] * ir);
  }
}

// ------------------------------------------------------- GEMM2: out proj
// 64x64 tile (grid 64x16 = 1024 blocks = 4 blocks/CU = 4 waves/SIMD):
// doubles TLP over the drained 1-phase staging loop vs the 64x128 tile
// (512 blocks = 2/CU). Extra Wot L2 traffic (2MB x 16 col-tiles = 32MB)
// is trivial vs 34 TB/s L2.
__global__ __launch_bounds__(256) void gemm_out(
    const _Float16* __restrict__ AO, const _Float16* __restrict__ Wot,
    const float* __restrict__ bo, float* __restrict__ out)
{
  __shared__ __align__(16) _Float16 As[64 * 64], Bs[64 * 64];   // 16 KB
  const int row0 = blockIdx.x * 64, col0 = blockIdx.y * 64;
  const int t = threadIdx.x, l = t & 63, l15 = l & 15, lg = l >> 4, w = t >> 6;
  const int wr = (w >> 1) * 32, wc = (w & 1) * 32;
  const int lsub = l >> 3, lcb = (l & 7) * 16;
  f32x4 acc[2][2];
#pragma unroll
  for (int m = 0; m < 2; ++m)
#pragma unroll
    for (int n = 0; n < 2; ++n)
      acc[m][n] = (f32x4){0.f, 0.f, 0.f, 0.f};

  for (int k0 = 0; k0 < 1024; k0 += 64) {
    __syncthreads();
    // A tile: 64 rows (16 per wave); B tile: 64 rows (16 per wave)
#pragma unroll
    for (int i = 0; i < 2; ++i) {
      const int rb = w * 16 + i * 8;
      const int r = rb + lsub;
      const int swz = lcb ^ ((r & 7) << 4);
      gload16((const char*)AO + (size_t)(row0 + r) * 2048 + (size_t)k0 * 2 + swz,
              (char*)As + rb * 128);
      gload16((const char*)Wot + (size_t)(col0 + r) * 2048 + (size_t)k0 * 2 + swz,
              (char*)Bs + rb * 128);
    }
    __syncthreads();
#pragma unroll
    for (int kk = 0; kk < 2; ++kk) {
      const int kb = kk * 64 + (lg << 4);
      half8 af[2], bf[2];
#pragma unroll
      for (int m = 0; m < 2; ++m) {
        const int row = wr + 16 * m + l15;
        af[m] = *(const half8*)((const char*)As + row * 128 + (kb ^ ((row & 7) << 4)));
      }
#pragma unroll
      for (int n = 0; n < 2; ++n) {
        const int col = wc + 16 * n + l15;
        bf[n] = *(const half8*)((const char*)Bs + col * 128 + (kb ^ ((col & 7) << 4)));
      }
#pragma unroll
      for (int m = 0; m < 2; ++m)
#pragma unroll
        for (int n = 0; n < 2; ++n)
          acc[m][n] = __builtin_amdgcn_mfma_f32_16x16x32_f16(af[m], bf[n], acc[m][n], 0, 0, 0);
    }
  }

  const int wrow = row0 + wr, wcol = col0 + wc;
  float b[2];
#pragma unroll
  for (int n = 0; n < 2; ++n) b[n] = bo[wcol + 16 * n + l15];
#pragma unroll
  for (int m = 0; m < 2; ++m)
#pragma unroll
    for (int reg = 0; reg < 4; ++reg) {
      const int row = wrow + 16 * m + lg * 4 + reg;
#pragma unroll
      for (int n = 0; n < 2; ++n)
        out[(size_t)row * 1024 + wcol + 16 * n + l15] = acc[m][n][reg] + b[n];
    }
}

// ---------------------------------------------------------------- launch
extern "C" void kernel_launch(void* const* d_in, const int* in_sizes, int n_in,
                              void* d_out, int out_size, void* d_ws, size_t ws_size,
                              hipStream_t stream)
{
  const float* x   = (const float*)d_in[0];
  const float* Wq  = (const float*)d_in[1];
  const float* bq  = (const float*)d_in[2];
  const float* Wkv = (const float*)d_in[3];
  const float* bkv = (const float*)d_in[4];
  const float* Wo  = (const float*)d_in[5];
  const float* bo  = (const float*)d_in[6];
  float* out = (float*)d_out;
  char* ws = (char*)d_ws;

  _Float16* xb  = (_Float16*)(ws);
  _Float16* Wt  = (_Float16*)(ws + 8388608);
  _Float16* Wot = (_Float16*)(ws + 14680064);
  float2*   cs  = (float2*)  (ws + 16777216);
  _Float16* Qb  = (_Float16*)(ws + 17301504);
  _Float16* Kb  = (_Float16*)(ws + 25690112);
  _Float16* Vt  = (_Float16*)(ws + 34078720);
  _Float16* AO  = (_Float16*)(ws + 42467328);

  prep_kernel<<<6400, 256, 0, stream>>>(x, Wq, Wkv, Wo, xb, Wt, Wot, cs);
  gemm_qkv<<<dim3(32, 24), 256, 0, stream>>>(xb, Wt, bq, bkv, cs, Qb, Kb, Vt);
  attn_kernel<<<dim3(16, 32), 256, 0, stream>>>(Qb, Kb, Vt, AO);
  gemm_out<<<dim3(64, 16), 256, 0, stream>>>(AO, Wot, bo, out);
}

// Round 24
// 105.665 us; speedup vs baseline: 1.2811x; 1.0718x over previous
//
#include <hip/hip_runtime.h>
#include <hip/hip_bf16.h>
#include <math.h>

// Problem: B=2, T=2048, D=1024, H=16, C=64. fp32 in/out, fp16 MFMA internally.
//
// Workspace layout (bytes):
//   xb  @ 0         : x as fp16            (4096x1024)   8388608
//   Wt  @ 8388608   : [Wq;Wkv]^T fp16      (3072x1024)   6291456
//   Wot @ 14680064  : Wo^T fp16            (1024x1024)   2097152
//   cs  @ 16777216  : cos/sin table float2 (2048x32)      524288
//   Qb  @ 17301504  : Q roped*scale fp16 [B][H][T][C]    8388608
//   Kb  @ 25690112  : K roped fp16 [B][H][T][C]          8388608
//   Vt  @ 34078720  : V fp16 [B][H][C][T] (transposed)   8388608
//   AO  @ 42467328  : attention out fp16 [B*T][H*C]      8388608
//
// r24: gemm_qkv ported to the proven 64x128 core (= gemm_out r17 core):
// 1536 blocks = 6 blocks/CU = 6 waves/SIMD (24KB LDS/block), decoded as
// 1024 QK blocks (64 t x 128 qk-cols) + 512 V blocks (64 v-ch x 128 t,
// r17 transposed-V contiguous stores). Mirrors the r17/r23 gemm_out wins
// (more TLP over the drained 2-barrier staging loop).
// Ledger: r21 V-direct regressed (gload_lds is VGPR-free DMA); r19
// XCD-chunking + attn setprio regressed; r18 KVBLK=128; r16 native exp2 +
// builtin permlane (attn 71->54); r17 V-transposed epilogue.

typedef _Float16 half8 __attribute__((ext_vector_type(8)));
typedef _Float16 half4 __attribute__((ext_vector_type(4)));
typedef float f32x4 __attribute__((ext_vector_type(4)));
typedef float f32x16 __attribute__((ext_vector_type(16)));

// OCML native exp2 = raw v_exp_f32, compiler-visible (r16: libm exp2f's
// fixup tail was ~18% of attn VALU; builtin permlane closed the r13/r15
// inline-asm hazard).
extern "C" __device__ float __ocml_native_exp2_f32(float);

__device__ __forceinline__ void gload16(const void* g, void* l) {
  __builtin_amdgcn_global_load_lds(
      (const __attribute__((address_space(1))) void*)g,
      (__attribute__((address_space(3))) void*)l, 16, 0, 0);
}

// ---------------------------------------------------------------- prep
__global__ __launch_bounds__(256) void prep_kernel(
    const float* __restrict__ x, const float* __restrict__ Wq,
    const float* __restrict__ Wkv, const float* __restrict__ Wo,
    _Float16* __restrict__ xb, _Float16* __restrict__ Wt,
    _Float16* __restrict__ Wot, float2* __restrict__ cs)
{
  const int bid = blockIdx.x, t = threadIdx.x;
  if (bid < 2048) {
    size_t i = ((size_t)bid * 256 + t) * 8;
    const float4* p = (const float4*)(x + i);
    float4 a = p[0], b = p[1];
    half8 h;
    h[0] = (_Float16)a.x; h[1] = (_Float16)a.y; h[2] = (_Float16)a.z; h[3] = (_Float16)a.w;
    h[4] = (_Float16)b.x; h[5] = (_Float16)b.y; h[6] = (_Float16)b.z; h[7] = (_Float16)b.w;
    *(half8*)(xb + i) = h;
  } else if (bid < 6144) {
    int tt = bid - 2048;
    const float* src; _Float16* dst; int N, tk, tn;
    if (tt < 1024)      { src = Wq;  dst = Wt;                      N = 1024; tk = tt >> 5; tn = tt & 31; }
    else if (tt < 3072) { tt -= 1024; src = Wkv; dst = Wt + (size_t)1024 * 1024; N = 2048; tk = tt >> 6; tn = tt & 63; }
    else                { tt -= 3072; src = Wo;  dst = Wot;         N = 1024; tk = tt >> 5; tn = tt & 31; }
    __shared__ float tile[32][33];
    const int r = t >> 3, c4 = (t & 7) << 2;
    const float4 v = *(const float4*)(src + (size_t)(tk * 32 + r) * N + tn * 32 + c4);
    tile[r][c4 + 0] = v.x; tile[r][c4 + 1] = v.y; tile[r][c4 + 2] = v.z; tile[r][c4 + 3] = v.w;
    __syncthreads();
    half4 o;
    o[0] = (_Float16)tile[c4 + 0][r];
    o[1] = (_Float16)tile[c4 + 1][r];
    o[2] = (_Float16)tile[c4 + 2][r];
    o[3] = (_Float16)tile[c4 + 3][r];
    *(half4*)(dst + (size_t)(tn * 32 + r) * 1024 + tk * 32 + c4) = o;
  } else {
    int idx = (bid - 6144) * 256 + t;
    int tt = idx >> 5, j = idx & 31;
    float p = powf(10000.0f, (float)(2 * j) * (1.0f / 64.0f));
    float ang = (float)tt / p;
    float sn, cn;
    sincosf(ang, &sn, &cn);
    cs[idx] = make_float2(cn, sn);
  }
}

// ------------------------------------------------------- GEMM1: QKV+RoPE
// 64x128 tiles, 1536 blocks (1D): bid<1024 -> QK (rows = 64 t, cols = 128
// qk-channels); bid>=1024 -> V transposed (rows = 64 v-channels, cols =
// 128 t) so Vt[c][t] stores stay contiguous in t (r17). Q pre-scaled by
// (1/sqrt(C))*log2(e).
__global__ __launch_bounds__(256) void gemm_qkv(
    const _Float16* __restrict__ xb, const _Float16* __restrict__ Wt,
    const float* __restrict__ bq, const float* __restrict__ bkv,
    const float2* __restrict__ cs,
    _Float16* __restrict__ Qb, _Float16* __restrict__ Kb, _Float16* __restrict__ Vt)
{
  __shared__ __align__(16) _Float16 As[64 * 64], Bs[128 * 64];   // 24 KB
  const int bid = blockIdx.x;
  const int t = threadIdx.x, l = t & 63, l15 = l & 15, lg = l >> 4, w = t >> 6;
  const int wr = (w >> 1) * 32, wc = (w & 1) * 64;
  const int lsub = l >> 3, lcb = (l & 7) * 16;

  // decode: A-tile 64 rows (output rows), B-tile 128 rows (output cols)
  const _Float16* Ag; const _Float16* Bg;
  int arow0, brow0;
  if (bid < 1024) {                       // QK: A = xb (t), B = Wt (qk ch)
    arow0 = (bid >> 4) * 64;
    brow0 = (bid & 15) * 128;
    Ag = xb; Bg = Wt;
  } else {                                // V: A = Wt v-rows, B = xb (t)
    const int v = bid - 1024;
    arow0 = 2048 + (v >> 5) * 64;
    brow0 = (v & 31) * 128;
    Ag = Wt; Bg = xb;
  }

  f32x4 acc[2][4];
#pragma unroll
  for (int m = 0; m < 2; ++m)
#pragma unroll
    for (int n = 0; n < 4; ++n)
      acc[m][n] = (f32x4){0.f, 0.f, 0.f, 0.f};

  for (int k0 = 0; k0 < 1024; k0 += 64) {
    __syncthreads();
#pragma unroll
    for (int i = 0; i < 2; ++i) {
      const int rb = w * 16 + i * 8;
      const int r = rb + lsub;
      const int swz = lcb ^ ((r & 7) << 4);
      gload16((const char*)Ag + (size_t)(arow0 + r) * 2048 + (size_t)k0 * 2 + swz,
              (char*)As + rb * 128);
    }
#pragma unroll
    for (int i = 0; i < 4; ++i) {
      const int rb = i * 32 + w * 8;
      const int r = rb + lsub;
      const int swz = lcb ^ ((r & 7) << 4);
      gload16((const char*)Bg + (size_t)(brow0 + r) * 2048 + (size_t)k0 * 2 + swz,
              (char*)Bs + rb * 128);
    }
    __syncthreads();
#pragma unroll
    for (int kk = 0; kk < 2; ++kk) {
      const int kb = kk * 64 + (lg << 4);
      half8 af[2], bf[4];
#pragma unroll
      for (int m = 0; m < 2; ++m) {
        const int row = wr + 16 * m + l15;
        af[m] = *(const half8*)((const char*)As + row * 128 + (kb ^ ((row & 7) << 4)));
      }
#pragma unroll
      for (int n = 0; n < 4; ++n) {
        const int col = wc + 16 * n + l15;
        bf[n] = *(const half8*)((const char*)Bs + col * 128 + (kb ^ ((col & 7) << 4)));
      }
#pragma unroll
      for (int m = 0; m < 2; ++m)
#pragma unroll
        for (int n = 0; n < 4; ++n)
          acc[m][n] = __builtin_amdgcn_mfma_f32_16x16x32_f16(af[m], bf[n], acc[m][n], 0, 0, 0);
    }
  }

  if (bid < 1024) {
    // ---------------- Q / K epilogue (RoPE; one head per 64-col wave span)
    const int wrow = arow0 + wr;
    const int ncol = brow0 + wc;
    const int seg = ncol >> 10;              // 0:q 1:k
    const int hcol = ncol & 1023;
    const int h = hcol >> 6;
    const float* bias = (seg == 0) ? bq : bkv;
    _Float16* dst = (seg == 0) ? Qb : Kb;
    const float qs = (seg == 0) ? 0.18033688011112042f : 1.0f;  // sl2e or 1
    const float b0 = bias[hcol + l15],      b1 = bias[hcol + 16 + l15];
    const float b2 = bias[hcol + 32 + l15], b3 = bias[hcol + 48 + l15];
#pragma unroll
    for (int m = 0; m < 2; ++m) {
#pragma unroll
      for (int reg = 0; reg < 4; ++reg) {
        const int row = wrow + 16 * m + lg * 4 + reg;
        const int bb = row >> 11, tt = row & 2047;
        const float2 cs0 = cs[tt * 32 + l15];
        const float2 cs1 = cs[tt * 32 + 16 + l15];
        const float v0 = acc[m][0][reg] + b0;
        const float v1 = acc[m][1][reg] + b1;
        const float v2 = acc[m][2][reg] + b2;
        const float v3 = acc[m][3][reg] + b3;
        const size_t base = ((size_t)(bb * 16 + h) * 2048 + tt) * 64;
        dst[base + l15]      = (_Float16)((v0 * cs0.x - v2 * cs0.y) * qs);
        dst[base + 16 + l15] = (_Float16)((v1 * cs1.x - v3 * cs1.y) * qs);
        dst[base + 32 + l15] = (_Float16)((v2 * cs0.x + v0 * cs0.y) * qs);
        dst[base + 48 + l15] = (_Float16)((v3 * cs1.x + v1 * cs1.y) * qs);
      }
    }
  } else {
    // ---------------- V epilogue (transposed; contiguous in t)
    const int vcol = (arow0 - 2048) + wr;    // wave's base v-channel
    const int tbase = brow0 + wc;            // wave's base t
#pragma unroll
    for (int m = 0; m < 2; ++m) {
#pragma unroll
      for (int reg = 0; reg < 4; ++reg) {
        const int vchan = vcol + 16 * m + lg * 4 + reg;      // 0..1023
        const float bv = bkv[1024 + vchan];
#pragma unroll
        for (int n = 0; n < 4; ++n) {
          const int tg = tbase + 16 * n + l15;
          const int bb2 = tg >> 11, tt2 = tg & 2047;
          Vt[((size_t)bb2 * 1024 + vchan) * 2048 + tt2] =
              (_Float16)(acc[m][n][reg] + bv);
        }
      }
    }
  }
}

// ------------------------------------------------------- flash attention
// r16 body + KVBLK=128: two 64-row KV sub-tiles per barrier region.
// 4 sub-buffers = 2 logical double-buffers (64 KB LDS, 2 blocks/CU).
__global__ __launch_bounds__(256, 2) void attn_kernel(
    const _Float16* __restrict__ Qb, const _Float16* __restrict__ Kb,
    const _Float16* __restrict__ Vt, _Float16* __restrict__ AO)
{
  __shared__ __align__(16) _Float16 Ks[4][64 * 64], Vs[4][64 * 64];   // 64 KB
  // bijective swizzle of 512 blocks: 8 XCDs x (4 bh x 16 qtiles)
  const int lin = blockIdx.x + (blockIdx.y << 4);
  const int xcd = lin & 7, idx = lin >> 3;          // idx 0..63
  const int bh = (xcd << 2) + (idx >> 4);
  const int qblk = (idx & 15) << 7;                 // 128 q rows per block
  const int t = threadIdx.x, l = t & 63, l31 = l & 31, hh = l >> 5, w = t >> 6;
  const _Float16* Qg = Qb + (size_t)bh * 2048 * 64;
  const _Float16* Kg = Kb + (size_t)bh * 2048 * 64;
  const _Float16* Vg = Vt + (size_t)bh * 64 * 2048;

  // Q fragments (B operand, 32x32x16): col=q=l31, k(c) = 32*t4 + 16*hh + j
  const int qrow = qblk + w * 32 + l31;
  half8 qf[4];
#pragma unroll
  for (int t4 = 0; t4 < 4; ++t4)
    qf[t4] = *(const half8*)((const char*)Qg + (size_t)qrow * 128 + t4 * 32 + hh * 16);

  f32x16 oacc[2], lacc;
#pragma unroll
  for (int cc = 0; cc < 2; ++cc)
#pragma unroll
    for (int r = 0; r < 16; ++r) oacc[cc][r] = 0.f;
#pragma unroll
  for (int r = 0; r < 16; ++r) lacc[r] = 0.f;
  const half8 onesf = {(_Float16)1, (_Float16)1, (_Float16)1, (_Float16)1,
                       (_Float16)1, (_Float16)1, (_Float16)1, (_Float16)1};

  const int lsub = l >> 3;
  const int lcb  = (l & 7) * 16;

#define STAGE(s0, buf)                                                          \
  {                                                                             \
    _Pragma("unroll")                                                           \
    for (int i = 0; i < 2; ++i) {                                               \
      const int rb = w * 16 + i * 8;                                            \
      const int r = rb + lsub;                                                  \
      const int swz = lcb ^ ((r & 7) << 4);                                     \
      gload16((const char*)Kg + (size_t)((s0) + r) * 128 + swz,                 \
              (char*)Ks[buf] + rb * 128);                                       \
      gload16((const char*)Vg + (size_t)r * 4096 + (size_t)(s0) * 2 + swz,      \
              (char*)Vs[buf] + rb * 128);                                       \
    }                                                                           \
  }

  const int ksw = (l31 & 7) << 4;    // swizzle for K rows (l31) and V rows

  // one 64-row KV sub-tile: QKT -> softmax (native exp2, builtin permlane)
  // -> PV + ones-column row sums
#define PROCESS(sb)                                                             \
  {                                                                             \
    f32x16 sacc[2];                                                             \
    _Pragma("unroll")                                                           \
    for (int s = 0; s < 2; ++s)                                                 \
      _Pragma("unroll")                                                         \
      for (int r = 0; r < 16; ++r) sacc[s][r] = 0.f;                            \
    _Pragma("unroll")                                                           \
    for (int s = 0; s < 2; ++s) {                                               \
      const int krow = 32 * s + l31;                                            \
      _Pragma("unroll")                                                         \
      for (int t4 = 0; t4 < 4; ++t4) {                                          \
        half8 kf = *(const half8*)((const char*)Ks[sb] + krow * 128 +           \
                                   ((32 * t4 + 16 * hh) ^ ksw));                \
        sacc[s] = __builtin_amdgcn_mfma_f32_32x32x16_f16(kf, qf[t4], sacc[s],   \
                                                         0, 0, 0);              \
      }                                                                         \
    }                                                                           \
    half8 pa[4];                                                                \
    _Pragma("unroll")                                                           \
    for (int s = 0; s < 2; ++s) {                                               \
      unsigned wpk[8];                                                          \
      _Pragma("unroll")                                                         \
      for (int i = 0; i < 8; ++i) {                                             \
        const float p0 = __ocml_native_exp2_f32(sacc[s][2 * i]);                \
        const float p1 = __ocml_native_exp2_f32(sacc[s][2 * i + 1]);            \
        const auto pk = __builtin_amdgcn_cvt_pkrtz(p0, p1);                     \
        __builtin_memcpy(&wpk[i], &pk, 4);                                      \
      }                                                                         \
      const auto r0 = __builtin_amdgcn_permlane32_swap(wpk[0], wpk[2], false, false); \
      const auto r1 = __builtin_amdgcn_permlane32_swap(wpk[1], wpk[3], false, false); \
      const auto r2 = __builtin_amdgcn_permlane32_swap(wpk[4], wpk[6], false, false); \
      const auto r3 = __builtin_amdgcn_permlane32_swap(wpk[5], wpk[7], false, false); \
      union { unsigned u[4]; half8 v; } lo, hi;                                 \
      lo.u[0] = r0[0]; lo.u[1] = r1[0]; lo.u[2] = r0[1]; lo.u[3] = r1[1];       \
      hi.u[0] = r2[0]; hi.u[1] = r3[0]; hi.u[2] = r2[1]; hi.u[3] = r3[1];       \
      pa[2 * s] = lo.v;                                                         \
      pa[2 * s + 1] = hi.v;                                                     \
    }                                                                           \
    _Pragma("unroll")                                                           \
    for (int t4 = 0; t4 < 4; ++t4) {                                            \
      lacc = __builtin_amdgcn_mfma_f32_32x32x16_f16(pa[t4], onesf, lacc, 0, 0, 0); \
      _Pragma("unroll")                                                         \
      for (int cc = 0; cc < 2; ++cc) {                                          \
        const int vrow = 32 * cc + l31;                                         \
        half8 vf = *(const half8*)((const char*)Vs[sb] + vrow * 128 +           \
                                   ((32 * t4 + 16 * hh) ^ ksw));                \
        oacc[cc] = __builtin_amdgcn_mfma_f32_32x32x16_f16(pa[t4], vf, oacc[cc], \
                                                          0, 0, 0);             \
      }                                                                         \
    }                                                                           \
  }

  // prologue: logical buffer 0 = sub-buffers {0,1} = kv tiles 0,1
  STAGE(0, 0);
  STAGE(64, 1);
  asm volatile("s_waitcnt vmcnt(0)" ::: "memory");
  __builtin_amdgcn_s_barrier();

  for (int it = 0; it < 16; ++it) {
    const int base = (it & 1) << 1;          // sub-buffers {base, base+1}
    const int sbase = (base ^ 2);            // staging pair
    if (it < 15) {
      STAGE((2 * it + 2) * 64, sbase);
      STAGE((2 * it + 3) * 64, sbase + 1);
    }
    PROCESS(base);
    PROCESS(base + 1);
    if (it < 15) {
      asm volatile("s_waitcnt vmcnt(0)" ::: "memory");
      __builtin_amdgcn_s_barrier();
    }
  }
#undef PROCESS
#undef STAGE

  // ---- normalize + store: oacc[cc][reg] = O[q=(reg&3)+8(reg>>2)+4hh][c=32cc+l31]
  const int bb = bh >> 4, hd = bh & 15;
#pragma unroll
  for (int reg = 0; reg < 16; ++reg) {
    const int q = qblk + w * 32 + (reg & 3) + 8 * (reg >> 2) + 4 * hh;
    const float ir = 1.0f / lacc[reg];
    const size_t base = ((size_t)bb * 2048 + q) * 1024 + hd * 64;
    AO[base + l31]      = (_Float16)(oacc[0][reg] * ir);
    AO[base + 32 + l31] = (_Float16)(oacc[1][reg] * ir);
  }
}

// ------------------------------------------------------- GEMM2: out proj
// 64x64 tile (grid 64x16 = 1024 blocks = 4 blocks/CU = 4 waves/SIMD).
__global__ __launch_bounds__(256) void gemm_out(
    const _Float16* __restrict__ AO, const _Float16* __restrict__ Wot,
    const float* __restrict__ bo, float* __restrict__ out)
{
  __shared__ __align__(16) _Float16 As[64 * 64], Bs[64 * 64];   // 16 KB
  const int row0 = blockIdx.x * 64, col0 = blockIdx.y * 64;
  const int t = threadIdx.x, l = t & 63, l15 = l & 15, lg = l >> 4, w = t >> 6;
  const int wr = (w >> 1) * 32, wc = (w & 1) * 32;
  const int lsub = l >> 3, lcb = (l & 7) * 16;
  f32x4 acc[2][2];
#pragma unroll
  for (int m = 0; m < 2; ++m)
#pragma unroll
    for (int n = 0; n < 2; ++n)
      acc[m][n] = (f32x4){0.f, 0.f, 0.f, 0.f};

  for (int k0 = 0; k0 < 1024; k0 += 64) {
    __syncthreads();
#pragma unroll
    for (int i = 0; i < 2; ++i) {
      const int rb = w * 16 + i * 8;
      const int r = rb + lsub;
      const int swz = lcb ^ ((r & 7) << 4);
      gload16((const char*)AO + (size_t)(row0 + r) * 2048 + (size_t)k0 * 2 + swz,
              (char*)As + rb * 128);
      gload16((const char*)Wot + (size_t)(col0 + r) * 2048 + (size_t)k0 * 2 + swz,
              (char*)Bs + rb * 128);
    }
    __syncthreads();
#pragma unroll
    for (int kk = 0; kk < 2; ++kk) {
      const int kb = kk * 64 + (lg << 4);
      half8 af[2], bf[2];
#pragma unroll
      for (int m = 0; m < 2; ++m) {
        const int row = wr + 16 * m + l15;
        af[m] = *(const half8*)((const char*)As + row * 128 + (kb ^ ((row & 7) << 4)));
      }
#pragma unroll
      for (int n = 0; n < 2; ++n) {
        const int col = wc + 16 * n + l15;
        bf[n] = *(const half8*)((const char*)Bs + col * 128 + (kb ^ ((col & 7) << 4)));
      }
#pragma unroll
      for (int m = 0; m < 2; ++m)
#pragma unroll
        for (int n = 0; n < 2; ++n)
          acc[m][n] = __builtin_amdgcn_mfma_f32_16x16x32_f16(af[m], bf[n], acc[m][n], 0, 0, 0);
    }
  }

  const int wrow = row0 + wr, wcol = col0 + wc;
  float b[2];
#pragma unroll
  for (int n = 0; n < 2; ++n) b[n] = bo[wcol + 16 * n + l15];
#pragma unroll
  for (int m = 0; m < 2; ++m)
#pragma unroll
    for (int reg = 0; reg < 4; ++reg) {
      const int row = wrow + 16 * m + lg * 4 + reg;
#pragma unroll
      for (int n = 0; n < 2; ++n)
        out[(size_t)row * 1024 + wcol + 16 * n + l15] = acc[m][n][reg] + b[n];
    }
}

// ---------------------------------------------------------------- launch
extern "C" void kernel_launch(void* const* d_in, const int* in_sizes, int n_in,
                              void* d_out, int out_size, void* d_ws, size_t ws_size,
                              hipStream_t stream)
{
  const float* x   = (const float*)d_in[0];
  const float* Wq  = (const float*)d_in[1];
  const float* bq  = (const float*)d_in[2];
  const float* Wkv = (const float*)d_in[3];
  const float* bkv = (const float*)d_in[4];
  const float* Wo  = (const float*)d_in[5];
  const float* bo  = (const float*)d_in[6];
  float* out = (float*)d_out;
  char* ws = (char*)d_ws;

  _Float16* xb  = (_Float16*)(ws);
  _Float16* Wt  = (_Float16*)(ws + 8388608);
  _Float16* Wot = (_Float16*)(ws + 14680064);
  float2*   cs  = (float2*)  (ws + 16777216);
  _Float16* Qb  = (_Float16*)(ws + 17301504);
  _Float16* Kb  = (_Float16*)(ws + 25690112);
  _Float16* Vt  = (_Float16*)(ws + 34078720);
  _Float16* AO  = (_Float16*)(ws + 42467328);

  prep_kernel<<<6400, 256, 0, stream>>>(x, Wq, Wkv, Wo, xb, Wt, Wot, cs);
  gemm_qkv<<<1536, 256, 0, stream>>>(xb, Wt, bq, bkv, cs, Qb, Kb, Vt);
  attn_kernel<<<dim3(16, 32), 256, 0, stream>>>(Qb, Kb, Vt, AO);
  gemm_out<<<dim3(64, 16), 256, 0, stream>>>(AO, Wot, bo, out);
}